// Round 7
// baseline (3715.981 us; speedup 1.0000x reference)
//
#include <hip/hip_runtime.h>

typedef _Float16 f16;
typedef _Float16 half8 __attribute__((ext_vector_type(8)));
typedef float f32x4 __attribute__((ext_vector_type(4)));
typedef int i32x4 __attribute__((ext_vector_type(4)));

#define SEQ 512
#define NB 128
#define NH 768
#define NFEAT 128
#define NGRP 4
#define BG 32
#define NCOL 48
#define NWG (NGRP*NCOL)
#define KW8 96

// workspace layout
#define OFF_WIH   0LL
#define OFF_WHH   3538944LL
#define OFF_WLIN  7077888LL
#define OFF_XBUF  7274496LL
#define OFF_HBUF  7471104LL
#define OFF_CTR   7667712LL   /* 4 groups * 512 steps * 4B = 8 KB (16 KB reserved) */
#define OFF_Y     7684096LL
#define OFF_TN    108347392LL
#define WS_NEED   (OFF_TN + 1024)

__global__ void fill_sentinel(float* out, long long n) {
  long long i = (long long)blockIdx.x * blockDim.x + threadIdx.x;
  long long stride = (long long)gridDim.x * blockDim.x;
  for (; i < n; i += stride) out[i] = -2.0f;
}

__global__ void prep_kernel(const float* __restrict__ Ho, const float* __restrict__ Hn,
                            const unsigned int* __restrict__ Traw,
                            const float* __restrict__ Wih, const float* __restrict__ Whh,
                            const float* __restrict__ Wlin,
                            f16* __restrict__ wih16, f16* __restrict__ whh16,
                            f16* __restrict__ wlin16,
                            f16* __restrict__ xbuf, f16* __restrict__ hbuf,
                            int* __restrict__ Tn)
{
  long long idx = (long long)blockIdx.x * blockDim.x + threadIdx.x;
  long long stride = (long long)gridDim.x * blockDim.x;
  for (long long i = idx; i < 2304LL * 768LL; i += stride) {
    wih16[i] = (f16)Wih[i];
    whh16[i] = (f16)Whh[i];
  }
  for (long long i = idx; i < 128LL * 768LL; i += stride) {
    long long b = i / 768, h = i % 768;
    wlin16[i] = (f16)Wlin[i];
    xbuf[i] = (f16)Ho[(b * 32 + 31) * 768 + h];   // H_o[:, -1, :]
    hbuf[i] = (f16)Hn[i];                          // H_n[0]
  }
  // Normalize T: detect int64 (all odd 32-bit words zero) vs int32.
  if (blockIdx.x == 0 && threadIdx.x < 128) {
    bool allz = true;
    for (int i = 0; i < 64; ++i) allz = allz && (Traw[2 * i + 1] == 0u);
    int t = threadIdx.x;
    Tn[t] = allz ? (int)Traw[2 * t] : (int)Traw[t];
  }
}

// issue 3 b128 loads from base (+0/+64/+128 B) without compiler tracking;
// drained by the vmcnt(0) inside the next __syncthreads().
#define PF3(d0, d1, d2, b) do {                                                \
  asm volatile("global_load_dwordx4 %0, %1, off"            : "=v"(d0) : "v"(b)); \
  asm volatile("global_load_dwordx4 %0, %1, off offset:64"  : "=v"(d1) : "v"(b)); \
  asm volatile("global_load_dwordx4 %0, %1, off offset:128" : "=v"(d2) : "v"(b)); \
} while (0)

__global__ void __launch_bounds__(512, 1)
gru_kernel(const f16* __restrict__ wih16, const f16* __restrict__ whh16,
           const f16* __restrict__ xbuf, const f16* __restrict__ hbuf,
           const float* __restrict__ Hn,
           const float* __restrict__ b_ih, const float* __restrict__ b_hh,
           f16* __restrict__ Y, unsigned int* __restrict__ ctr)
{
  const int wg  = blockIdx.x;
  const int g   = wg & (NGRP - 1);   // batch group 0..3
  const int c   = wg >> 2;           // column slice 0..47
  const int tid = threadIdx.x;
  const int lane = tid & 63;
  const int wv  = tid >> 6;          // wave 0..7 (K-split)
  const int j0  = c * 16;
  const int ks  = wv * KW8;
  const int bbase = g * BG;

  // flat partial buffer: [wv][tile(12)][lane] of f32x4  (98304 B -> 1 WG/CU)
  __shared__ float pbuf[8 * 12 * 64 * 4];

  const int n15 = lane & 15;
  const int kg8 = (lane >> 4) * 8;

  // loop-invariant weight base addresses (one per gate row)
  const f16* wb0 = wih16 + (size_t)(0 * 768 + j0 + n15) * NH + ks + kg8;
  const f16* wb1 = wih16 + (size_t)(1 * 768 + j0 + n15) * NH + ks + kg8;
  const f16* wb2 = wih16 + (size_t)(2 * 768 + j0 + n15) * NH + ks + kg8;
  const f16* wb3 = whh16 + (size_t)(0 * 768 + j0 + n15) * NH + ks + kg8;
  const f16* wb4 = whh16 + (size_t)(1 * 768 + j0 + n15) * NH + ks + kg8;
  const f16* wb5 = whh16 + (size_t)(2 * 768 + j0 + n15) * NH + ks + kg8;

  // gate-phase assignment: one (batch, col) per thread; h carried in fp32 register
  const int gb = tid >> 4;           // 0..31 batch within group
  const int gj = tid & 15;
  const int jglob = j0 + gj;
  float hcarry = Hn[(size_t)(bbase + gb) * NH + jglob];
  const float bi_r = b_ih[jglob], bi_z = b_ih[768 + jglob], bi_n = b_ih[1536 + jglob];
  const float bh_r = b_hh[jglob], bh_z = b_hh[768 + jglob], bh_n = b_hh[1536 + jglob];

  const size_t arow0 = (size_t)(bbase + n15) * NH + ks + kg8;
  const size_t arow1 = arow0 + (size_t)16 * NH;
  const size_t ywr   = (size_t)(bbase + gb) * NH + jglob;

  // gate-phase read offset (value (m=gb,n=gj), tile rt=gb>>4)
  const int rt_g = gb >> 4, mt = gb & 15;
  const int off0 = rt_g * 1536 + (((mt >> 2) * 16 + gj) << 2) + (mt & 3);

  unsigned int* cbase = ctr + ((size_t)g << 9);

  for (int s = 0; s < SEQ; ++s) {
    // ---- 1. issue weight prefetch (lands during the sync wait) ----
    i32x4 w00, w01, w02, w10, w11, w12, w20, w21, w22;
    i32x4 w30, w31, w32, w40, w41, w42, w50, w51, w52;
    PF3(w00, w01, w02, wb0);
    PF3(w10, w11, w12, wb1);
    PF3(w20, w21, w22, wb2);
    PF3(w30, w31, w32, wb3);
    PF3(w40, w41, w42, wb4);
    PF3(w50, w51, w52, wb5);

    // ---- 2. wait for all 48 column-WGs of this group to finish step s-1 ----
    if (s > 0 && tid == 0) {
      unsigned int* cp = cbase + (s - 1);
      while (__hip_atomic_load(cp, __ATOMIC_RELAXED, __HIP_MEMORY_SCOPE_AGENT) < NCOL)
        __builtin_amdgcn_s_sleep(1);
    }
    __syncthreads();                       // C: release + drains prefetch loads
    __builtin_amdgcn_sched_barrier(0);     // pin MFMAs below the drain

    half8 B00 = __builtin_bit_cast(half8, w00), B01 = __builtin_bit_cast(half8, w01), B02 = __builtin_bit_cast(half8, w02);
    half8 B10 = __builtin_bit_cast(half8, w10), B11 = __builtin_bit_cast(half8, w11), B12 = __builtin_bit_cast(half8, w12);
    half8 B20 = __builtin_bit_cast(half8, w20), B21 = __builtin_bit_cast(half8, w21), B22 = __builtin_bit_cast(half8, w22);
    half8 B30 = __builtin_bit_cast(half8, w30), B31 = __builtin_bit_cast(half8, w31), B32 = __builtin_bit_cast(half8, w32);
    half8 B40 = __builtin_bit_cast(half8, w40), B41 = __builtin_bit_cast(half8, w41), B42 = __builtin_bit_cast(half8, w42);
    half8 B50 = __builtin_bit_cast(half8, w50), B51 = __builtin_bit_cast(half8, w51), B52 = __builtin_bit_cast(half8, w52);

    const f16* hsrc = (s == 0) ? hbuf : (Y + (size_t)(s - 1) * (NB * NH));
    const f16* xsrc = (s == 0) ? xbuf : hsrc;

    half8 Af0_0 = *(const half8*)(xsrc + arow0);
    half8 Af0_1 = *(const half8*)(xsrc + arow0 + 32);
    half8 Af0_2 = *(const half8*)(xsrc + arow0 + 64);
    half8 Af1_0 = *(const half8*)(xsrc + arow1);
    half8 Af1_1 = *(const half8*)(xsrc + arow1 + 32);
    half8 Af1_2 = *(const half8*)(xsrc + arow1 + 64);

    f32x4 a00 = {0.f,0.f,0.f,0.f}, a01 = {0.f,0.f,0.f,0.f}, a02 = {0.f,0.f,0.f,0.f};
    f32x4 a03 = {0.f,0.f,0.f,0.f}, a04 = {0.f,0.f,0.f,0.f}, a05 = {0.f,0.f,0.f,0.f};
    f32x4 a10 = {0.f,0.f,0.f,0.f}, a11 = {0.f,0.f,0.f,0.f}, a12 = {0.f,0.f,0.f,0.f};
    f32x4 a13 = {0.f,0.f,0.f,0.f}, a14 = {0.f,0.f,0.f,0.f}, a15 = {0.f,0.f,0.f,0.f};

    // ih gates (use x)
    a00 = __builtin_amdgcn_mfma_f32_16x16x32_f16(Af0_0, B00, a00, 0, 0, 0);
    a01 = __builtin_amdgcn_mfma_f32_16x16x32_f16(Af0_0, B10, a01, 0, 0, 0);
    a02 = __builtin_amdgcn_mfma_f32_16x16x32_f16(Af0_0, B20, a02, 0, 0, 0);
    a10 = __builtin_amdgcn_mfma_f32_16x16x32_f16(Af1_0, B00, a10, 0, 0, 0);
    a11 = __builtin_amdgcn_mfma_f32_16x16x32_f16(Af1_0, B10, a11, 0, 0, 0);
    a12 = __builtin_amdgcn_mfma_f32_16x16x32_f16(Af1_0, B20, a12, 0, 0, 0);
    a00 = __builtin_amdgcn_mfma_f32_16x16x32_f16(Af0_1, B01, a00, 0, 0, 0);
    a01 = __builtin_amdgcn_mfma_f32_16x16x32_f16(Af0_1, B11, a01, 0, 0, 0);
    a02 = __builtin_amdgcn_mfma_f32_16x16x32_f16(Af0_1, B21, a02, 0, 0, 0);
    a10 = __builtin_amdgcn_mfma_f32_16x16x32_f16(Af1_1, B01, a10, 0, 0, 0);
    a11 = __builtin_amdgcn_mfma_f32_16x16x32_f16(Af1_1, B11, a11, 0, 0, 0);
    a12 = __builtin_amdgcn_mfma_f32_16x16x32_f16(Af1_1, B21, a12, 0, 0, 0);
    a00 = __builtin_amdgcn_mfma_f32_16x16x32_f16(Af0_2, B02, a00, 0, 0, 0);
    a01 = __builtin_amdgcn_mfma_f32_16x16x32_f16(Af0_2, B12, a01, 0, 0, 0);
    a02 = __builtin_amdgcn_mfma_f32_16x16x32_f16(Af0_2, B22, a02, 0, 0, 0);
    a10 = __builtin_amdgcn_mfma_f32_16x16x32_f16(Af1_2, B02, a10, 0, 0, 0);
    a11 = __builtin_amdgcn_mfma_f32_16x16x32_f16(Af1_2, B12, a11, 0, 0, 0);
    a12 = __builtin_amdgcn_mfma_f32_16x16x32_f16(Af1_2, B22, a12, 0, 0, 0);

    if (s == 0) {   // hh gates use h0, not x0
      Af0_0 = *(const half8*)(hbuf + arow0);
      Af0_1 = *(const half8*)(hbuf + arow0 + 32);
      Af0_2 = *(const half8*)(hbuf + arow0 + 64);
      Af1_0 = *(const half8*)(hbuf + arow1);
      Af1_1 = *(const half8*)(hbuf + arow1 + 32);
      Af1_2 = *(const half8*)(hbuf + arow1 + 64);
    }

    // hh gates (use h)
    a03 = __builtin_amdgcn_mfma_f32_16x16x32_f16(Af0_0, B30, a03, 0, 0, 0);
    a04 = __builtin_amdgcn_mfma_f32_16x16x32_f16(Af0_0, B40, a04, 0, 0, 0);
    a05 = __builtin_amdgcn_mfma_f32_16x16x32_f16(Af0_0, B50, a05, 0, 0, 0);
    a13 = __builtin_amdgcn_mfma_f32_16x16x32_f16(Af1_0, B30, a13, 0, 0, 0);
    a14 = __builtin_amdgcn_mfma_f32_16x16x32_f16(Af1_0, B40, a14, 0, 0, 0);
    a15 = __builtin_amdgcn_mfma_f32_16x16x32_f16(Af1_0, B50, a15, 0, 0, 0);
    a03 = __builtin_amdgcn_mfma_f32_16x16x32_f16(Af0_1, B31, a03, 0, 0, 0);
    a04 = __builtin_amdgcn_mfma_f32_16x16x32_f16(Af0_1, B41, a04, 0, 0, 0);
    a05 = __builtin_amdgcn_mfma_f32_16x16x32_f16(Af0_1, B51, a05, 0, 0, 0);
    a13 = __builtin_amdgcn_mfma_f32_16x16x32_f16(Af1_1, B31, a13, 0, 0, 0);
    a14 = __builtin_amdgcn_mfma_f32_16x16x32_f16(Af1_1, B41, a14, 0, 0, 0);
    a15 = __builtin_amdgcn_mfma_f32_16x16x32_f16(Af1_1, B51, a15, 0, 0, 0);
    a03 = __builtin_amdgcn_mfma_f32_16x16x32_f16(Af0_2, B32, a03, 0, 0, 0);
    a04 = __builtin_amdgcn_mfma_f32_16x16x32_f16(Af0_2, B42, a04, 0, 0, 0);
    a05 = __builtin_amdgcn_mfma_f32_16x16x32_f16(Af0_2, B52, a05, 0, 0, 0);
    a13 = __builtin_amdgcn_mfma_f32_16x16x32_f16(Af1_2, B32, a13, 0, 0, 0);
    a14 = __builtin_amdgcn_mfma_f32_16x16x32_f16(Af1_2, B42, a14, 0, 0, 0);
    a15 = __builtin_amdgcn_mfma_f32_16x16x32_f16(Af1_2, B52, a15, 0, 0, 0);

    // partials -> LDS, vectorized: 12 x ds_write_b128 per thread
    {
      f32x4* pb = (f32x4*)pbuf;
      const int wbase = wv * 768 + lane;      // f32x4 units
      pb[wbase +   0] = a00;  pb[wbase +  64] = a01;  pb[wbase + 128] = a02;
      pb[wbase + 192] = a03;  pb[wbase + 256] = a04;  pb[wbase + 320] = a05;
      pb[wbase + 384] = a10;  pb[wbase + 448] = a11;  pb[wbase + 512] = a12;
      pb[wbase + 576] = a13;  pb[wbase + 640] = a14;  pb[wbase + 704] = a15;
    }
    __syncthreads();   // A: partials visible

    // gate phase: reduce 8 wave-partials, apply GRU cell
    float gir = bi_r, giz = bi_z, gin = bi_n, ghr = bh_r, ghz = bh_z, ghn = bh_n;
#pragma unroll
    for (int ww = 0; ww < 8; ++ww) {
      const float* p = pbuf + ww * 3072 + off0;
      gir += p[0];    giz += p[256];  gin += p[512];
      ghr += p[768];  ghz += p[1024]; ghn += p[1280];
    }
    float rr = 1.f / (1.f + __expf(-(gir + ghr)));
    float zz = 1.f / (1.f + __expf(-(giz + ghz)));
    float xn = gin + rr * ghn;
    float nn = 1.f - 2.f / (__expf(2.f * xn) + 1.f);
    float hnew = (1.f - zz) * nn + zz * hcarry;
    hcarry = hnew;

    // pack pair (gj even|odd) into dword, agent-scope relaxed store -> LLC (sc1)
    unsigned int u = (unsigned int)__builtin_bit_cast(unsigned short, (f16)hnew);
    unsigned int partner = (unsigned int)__shfl_xor((int)u, 1);
    if ((tid & 1) == 0) {
      unsigned int val = u | (partner << 16);
      unsigned int* dst = (unsigned int*)(Y + (size_t)s * (NB * NH) + ywr);
      __hip_atomic_store(dst, val, __ATOMIC_RELAXED, __HIP_MEMORY_SCOPE_AGENT);
    }

    // B: each wave drains its vmcnt before s_barrier => all Y stores at LLC
    __syncthreads();
    if (tid == 0)
      __hip_atomic_fetch_add(cbase + s, 1u, __ATOMIC_RELAXED, __HIP_MEMORY_SCOPE_AGENT);
  }
}

__global__ void __launch_bounds__(256)
proj_kernel(const f16* __restrict__ Y, const f16* __restrict__ wlin16,
            const float* __restrict__ b_lin, const int* __restrict__ Tn,
            float* __restrict__ out)
{
  // rows r = s*128 + b over Y viewed as [512*128][768]; each WG does 64 rows x 128 cols
  const int tid = threadIdx.x;
  const int lane = tid & 63;
  const int wv = tid >> 6;
  const int r0 = blockIdx.x * 64 + wv * 16;
  const int n15 = lane & 15;
  const int kg8 = (lane >> 4) * 8;
  const size_t arow_off = (size_t)(r0 + n15) * NH + kg8;

  f32x4 acc[8];
#pragma unroll
  for (int nf = 0; nf < 8; ++nf) acc[nf] = (f32x4){0.f, 0.f, 0.f, 0.f};

  for (int kt = 0; kt < 24; ++kt) {
    half8 a = *(const half8*)(Y + arow_off + kt * 32);
#pragma unroll
    for (int nf = 0; nf < 8; ++nf) {
      half8 bfr = *(const half8*)(wlin16 + (size_t)(nf * 16 + n15) * NH + kt * 32 + kg8);
      acc[nf] = __builtin_amdgcn_mfma_f32_16x16x32_f16(a, bfr, acc[nf], 0, 0, 0);
    }
  }

#pragma unroll
  for (int nf = 0; nf < 8; ++nf) {
    int fcol = nf * 16 + n15;
    float bl = b_lin[fcol];
#pragma unroll
    for (int r = 0; r < 4; ++r) {
      int row = r0 + (lane >> 4) * 4 + r;
      int s = row >> 7, b = row & 127;
      int t = 511 - s;
      float v = (t < Tn[b]) ? (acc[nf][r] + bl) : -1.0f;
      out[((size_t)b * 512 + t) * NFEAT + fcol] = v;
    }
  }
}

extern "C" void kernel_launch(void* const* d_in, const int* in_sizes, int n_in,
                              void* d_out, int out_size, void* d_ws, size_t ws_size,
                              hipStream_t stream) {
  const float* Ho   = (const float*)d_in[0];
  const float* Hn   = (const float*)d_in[1];
  const unsigned int* Traw = (const unsigned int*)d_in[2];
  const float* Wih  = (const float*)d_in[3];
  const float* Whh  = (const float*)d_in[4];
  const float* bih  = (const float*)d_in[5];
  const float* bhh  = (const float*)d_in[6];
  const float* Wlin = (const float*)d_in[7];
  const float* blin = (const float*)d_in[8];
  float* out = (float*)d_out;

  if (ws_size < (size_t)WS_NEED) {
    fill_sentinel<<<1024, 256, 0, stream>>>(out, (long long)out_size);
    return;
  }

  char* ws = (char*)d_ws;
  f16* wih16  = (f16*)(ws + OFF_WIH);
  f16* whh16  = (f16*)(ws + OFF_WHH);
  f16* wlin16 = (f16*)(ws + OFF_WLIN);
  f16* xbuf   = (f16*)(ws + OFF_XBUF);
  f16* hbuf   = (f16*)(ws + OFF_HBUF);
  unsigned int* ctr = (unsigned int*)(ws + OFF_CTR);
  f16* Y      = (f16*)(ws + OFF_Y);
  int* Tn     = (int*)(ws + OFF_TN);

  hipMemsetAsync(ctr, 0, NGRP * SEQ * sizeof(unsigned int), stream);
  prep_kernel<<<512, 256, 0, stream>>>(Ho, Hn, Traw, Wih, Whh, Wlin,
                                       wih16, whh16, wlin16, xbuf, hbuf, Tn);
  gru_kernel<<<NWG, 512, 0, stream>>>(wih16, whh16, xbuf, hbuf, Hn, bih, bhh, Y, ctr);
  proj_kernel<<<1024, 256, 0, stream>>>(Y, wlin16, blin, Tn, out);
}